// Round 4
// baseline (1502.129 us; speedup 1.0000x reference)
//
#include <hip/hip_runtime.h>
#include <cstdint>
#include <cstddef>

// ---- problem constants ----
constexpr int Bn    = 512;
constexpr int NINT  = 1023;
constexpr int FLEAF = 64;
constexpr int FINT  = 32;
constexpr int Hh    = 128;
constexpr int OUTC  = 33;

#define THREADS 256
constexpr int KSTR  = 136;      // Act LDS k-stride (u16): 272B rows -> conflict-free b128
constexpr int MATSZ = 16384;    // u16 per half-matrix: 8 ntg x 4 kc x 64 lanes x 8

using short8 = __attribute__((ext_vector_type(8))) short;
using f32x4  = __attribute__((ext_vector_type(4))) float;

__device__ __forceinline__ unsigned int f2bf_rne_u(float f) {
  unsigned int u = __float_as_uint(f);
  u += 0x7fffu + ((u >> 16) & 1);
  return u;
}
__device__ __forceinline__ unsigned short f2bf_rne(float f) {
  return (unsigned short)(f2bf_rne_u(f) >> 16);
}
__device__ __forceinline__ float bf2f(unsigned short h) {
  return __uint_as_float((unsigned int)h << 16);
}
__device__ __forceinline__ float trunc_bf(float a) {
  return __uint_as_float(__float_as_uint(a) & 0xffff0000u);
}
__device__ __forceinline__ unsigned int pack_hi_trunc(float a, float b) {
  return (__float_as_uint(a) >> 16) | (__float_as_uint(b) & 0xffff0000u);
}
__device__ __forceinline__ unsigned int pack_lo_rne(float a, float b) {
  return (f2bf_rne_u(a) >> 16) | (f2bf_rne_u(b) & 0xffff0000u);
}

// Packed fragment-major weight frag address: ((ntg*4 + kc)*64 + lane)*8 u16 = 16B/lane.
__device__ __forceinline__ const short8* wfrag(const unsigned short* W, int ntg, int kc, int lane) {
  return (const short8*)&W[(((ntg << 2) + kc) << 6 | lane) << 3];
}

// Dense layer, wave grid 2x2 over a (MT*32)-row tile.
// wave wn owns n-half [64wn,64wn+64) (nt=4), wave wm owns rows [wm*MT*16, +MT*16).
// D = W x Act^T (A-op = W[n][k], B-op = Act[m][k]); C: col=m=l16, row=n=quad*4+r.
// In-place ReLU(Act @ W + b) into Ah/Al.
template <int KC, int MT>
__device__ __forceinline__ void dense_layer(
    unsigned short* Ah, unsigned short* Al,
    const unsigned short* __restrict__ Wh, const unsigned short* __restrict__ Wl,
    const float* __restrict__ bias)
{
  const int tid  = threadIdx.x;
  const int wave = tid >> 6;
  const int wn   = wave & 1;
  const int wm   = wave >> 1;
  const int lane = tid & 63;
  const int quad = lane >> 4;
  const int l16  = lane & 15;
  const int mbase = wm * MT * 16;

  // genuinely preload W-hi (KC*4 short8 = up to 64 VGPR) + bias
  short8 wh[4][KC];
#pragma unroll
  for (int nt = 0; nt < 4; ++nt)
#pragma unroll
    for (int kc = 0; kc < KC; ++kc)
      wh[nt][kc] = *wfrag(Wh, wn * 4 + nt, kc, lane);
  float4 bv[4];
#pragma unroll
  for (int nt = 0; nt < 4; ++nt)
    bv[nt] = *(const float4*)&bias[wn * 64 + nt * 16 + quad * 4];

  f32x4 c[MT][4];
#pragma unroll
  for (int mt = 0; mt < MT; ++mt)
#pragma unroll
    for (int nt = 0; nt < 4; ++nt) c[mt][nt] = (f32x4){0.f, 0.f, 0.f, 0.f};

#pragma unroll
  for (int kc = 0; kc < KC; ++kc) {
    const int k0 = kc * 32 + quad * 8;
    short8 wl[4];
#pragma unroll
    for (int nt = 0; nt < 4; ++nt) wl[nt] = *wfrag(Wl, wn * 4 + nt, kc, lane);
    short8 ah[MT], al[MT];
#pragma unroll
    for (int mt = 0; mt < MT; ++mt) {
      ah[mt] = *(const short8*)&Ah[(mbase + mt * 16 + l16) * KSTR + k0];
      al[mt] = *(const short8*)&Al[(mbase + mt * 16 + l16) * KSTR + k0];
    }
#pragma unroll
    for (int mt = 0; mt < MT; ++mt)
#pragma unroll
      for (int nt = 0; nt < 4; ++nt)
        c[mt][nt] = __builtin_amdgcn_mfma_f32_16x16x32_bf16(wh[nt][kc], ah[mt], c[mt][nt], 0, 0, 0);
#pragma unroll
    for (int mt = 0; mt < MT; ++mt)
#pragma unroll
      for (int nt = 0; nt < 4; ++nt)
        c[mt][nt] = __builtin_amdgcn_mfma_f32_16x16x32_bf16(wh[nt][kc], al[mt], c[mt][nt], 0, 0, 0);
#pragma unroll
    for (int mt = 0; mt < MT; ++mt)
#pragma unroll
      for (int nt = 0; nt < 4; ++nt)
        c[mt][nt] = __builtin_amdgcn_mfma_f32_16x16x32_bf16(wl[nt], ah[mt], c[mt][nt], 0, 0, 0);
  }
  __syncthreads();  // all Act reads complete before in-place overwrite

#pragma unroll
  for (int mt = 0; mt < MT; ++mt) {
    const int m = mbase + mt * 16 + l16;
#pragma unroll
    for (int nt = 0; nt < 4; ++nt) {
      const int nb = wn * 64 + nt * 16 + quad * 4;
      float v0 = fmaxf(c[mt][nt][0] + bv[nt].x, 0.f);
      float v1 = fmaxf(c[mt][nt][1] + bv[nt].y, 0.f);
      float v2 = fmaxf(c[mt][nt][2] + bv[nt].z, 0.f);
      float v3 = fmaxf(c[mt][nt][3] + bv[nt].w, 0.f);
      const unsigned int h0 = pack_hi_trunc(v0, v1);
      const unsigned int h1 = pack_hi_trunc(v2, v3);
      const unsigned int l0 = pack_lo_rne(v0 - trunc_bf(v0), v1 - trunc_bf(v1));
      const unsigned int l1 = pack_lo_rne(v2 - trunc_bf(v2), v3 - trunc_bf(v3));
      *(uint2*)&Ah[m * KSTR + nb] = make_uint2(h0, h1);
      *(uint2*)&Al[m * KSTR + nb] = make_uint2(l0, l1);
    }
  }
  __syncthreads();
}

// Output layer: [rows x 128] @ [128 x 33] + bias (linear), u16 hi/lo rows stride 33.
// wn=0 -> ntg {0,1}; wn=1 -> ntg {2}. Optional fp32 scalar (row0,n0) to finalOut.
template <int MT>
__device__ __forceinline__ void out_layer(
    const unsigned short* Ah, const unsigned short* Al,
    const unsigned short* __restrict__ Wh, const unsigned short* __restrict__ Wl,
    const float* __restrict__ bias,
    unsigned short* outH, unsigned short* outL, float* finalOut)
{
  const int tid  = threadIdx.x;
  const int wave = tid >> 6;
  const int wn   = wave & 1;
  const int wm   = wave >> 1;
  const int lane = tid & 63;
  const int quad = lane >> 4;
  const int l16  = lane & 15;
  const int mbase = wm * MT * 16;

#pragma unroll
  for (int nt = 0; nt < 2; ++nt) {
    const int ntg = wn * 2 + nt;
    if (ntg >= 3) continue;
    f32x4 c[MT];
#pragma unroll
    for (int mt = 0; mt < MT; ++mt) c[mt] = (f32x4){0.f, 0.f, 0.f, 0.f};
#pragma unroll
    for (int kc = 0; kc < 4; ++kc) {
      const int k0 = kc * 32 + quad * 8;
      const short8 bwh = *wfrag(Wh, ntg, kc, lane);
      const short8 bwl = *wfrag(Wl, ntg, kc, lane);
#pragma unroll
      for (int mt = 0; mt < MT; ++mt) {
        const short8 ah = *(const short8*)&Ah[(mbase + mt * 16 + l16) * KSTR + k0];
        const short8 al = *(const short8*)&Al[(mbase + mt * 16 + l16) * KSTR + k0];
        c[mt] = __builtin_amdgcn_mfma_f32_16x16x32_bf16(bwh, ah, c[mt], 0, 0, 0);
        c[mt] = __builtin_amdgcn_mfma_f32_16x16x32_bf16(bwh, al, c[mt], 0, 0, 0);
        c[mt] = __builtin_amdgcn_mfma_f32_16x16x32_bf16(bwl, ah, c[mt], 0, 0, 0);
      }
    }
    const int nb = ntg * 16 + quad * 4;
    const float4 bvv = *(const float4*)&bias[nb];
    const float bvr[4] = {bvv.x, bvv.y, bvv.z, bvv.w};
#pragma unroll
    for (int mt = 0; mt < MT; ++mt) {
      const int m = mbase + mt * 16 + l16;
#pragma unroll
      for (int r = 0; r < 4; ++r) {
        const int n = nb + r;
        const float v = c[mt][r] + bvr[r];
        if (n < OUTC) {
          outH[m * 33 + n] = (unsigned short)(__float_as_uint(v) >> 16);
          outL[m * 33 + n] = f2bf_rne(v - trunc_bf(v));
        }
        if (finalOut && n == 0 && m == 0) *finalOut = v;
      }
    }
  }
}

__global__ __launch_bounds__(THREADS, 2)
void leaf_kernel(const float* __restrict__ X,
                 const unsigned short* __restrict__ warena,
                 const float* __restrict__ barena,
                 unsigned short* __restrict__ outH, unsigned short* __restrict__ outL)
{
  __shared__ unsigned short Ah[128 * KSTR];
  __shared__ unsigned short Al[128 * KSTR];
  const int row_base = blockIdx.x * 128;
  const int tid = threadIdx.x;

  for (int e = tid; e < 128 * 16; e += THREADS) {
    const int r  = e >> 4;
    const int k0 = (e & 15) << 2;
    const float4 v = *(const float4*)&X[(size_t)(row_base + r) * FLEAF + k0];
    const unsigned int h0 = pack_hi_trunc(v.x, v.y);
    const unsigned int h1 = pack_hi_trunc(v.z, v.w);
    const unsigned int l0 = pack_lo_rne(v.x - trunc_bf(v.x), v.y - trunc_bf(v.y));
    const unsigned int l1 = pack_lo_rne(v.z - trunc_bf(v.z), v.w - trunc_bf(v.w));
    *(uint2*)&Ah[r * KSTR + k0] = make_uint2(h0, h1);
    *(uint2*)&Al[r * KSTR + k0] = make_uint2(l0, l1);
  }
  __syncthreads();

  dense_layer<2, 4>(Ah, Al, warena + 0 * 2 * MATSZ, warena + 0 * 2 * MATSZ + MATSZ, barena + 0 * 128);
#pragma unroll
  for (int l = 1; l <= 4; ++l)
    dense_layer<4, 4>(Ah, Al, warena + l * 2 * MATSZ, warena + l * 2 * MATSZ + MATSZ, barena + l * 128);
  out_layer<4>(Ah, Al, warena + 5 * 2 * MATSZ, warena + 5 * 2 * MATSZ + MATSZ, barena + 5 * 128,
               outH + (size_t)row_base * 33, outL + (size_t)row_base * 33, nullptr);
}

__global__ __launch_bounds__(THREADS, 2)
void int_kernel(const float* __restrict__ feat,
                const unsigned short* __restrict__ prevH, const unsigned short* __restrict__ prevL,
                const unsigned short* __restrict__ warena, const float* __restrict__ barena,
                unsigned short* __restrict__ outH, unsigned short* __restrict__ outL,
                int n, int logn)
{
  __shared__ unsigned short Ah[128 * KSTR];
  __shared__ unsigned short Al[128 * KSTR];
  const int tid = threadIdx.x;
  const int row0 = blockIdx.x * 128;

  // staging: one row per 64-lane group; chunks: 16 feat-u32, 33 child-u32, 15 zero-u32
  for (int e = tid; e < 128 * 64; e += THREADS) {
    const int m = e >> 6;
    const int c = e & 63;
    const int row = row0 + m;
    const int b = row >> logn;
    const int i = row & (n - 1);
    if (c < 16) {
      const float2 v = *(const float2*)&feat[((size_t)b * NINT + (n - 1) + i) * FINT + 2 * c];
      *(unsigned int*)&Ah[m * KSTR + 2 * c] = pack_hi_trunc(v.x, v.y);
      *(unsigned int*)&Al[m * KSTR + 2 * c] = pack_lo_rne(v.x - trunc_bf(v.x), v.y - trunc_bf(v.y));
    } else if (c < 49) {
      const int p = c - 16;
      const size_t c0 = ((size_t)b * (n << 1) + (i << 1)) * 33;
      *(unsigned int*)&Ah[m * KSTR + 32 + 2 * p] = *(const unsigned int*)&prevH[c0 + 2 * p];
      *(unsigned int*)&Al[m * KSTR + 32 + 2 * p] = *(const unsigned int*)&prevL[c0 + 2 * p];
    } else {
      const int z = c - 49;
      *(unsigned int*)&Ah[m * KSTR + 98 + 2 * z] = 0u;
      *(unsigned int*)&Al[m * KSTR + 98 + 2 * z] = 0u;
    }
  }
  __syncthreads();

#pragma unroll
  for (int l = 6; l <= 10; ++l)
    dense_layer<4, 4>(Ah, Al, warena + l * 2 * MATSZ, warena + l * 2 * MATSZ + MATSZ, barena + l * 128);
  out_layer<4>(Ah, Al, warena + 11 * 2 * MATSZ, warena + 11 * 2 * MATSZ + MATSZ, barena + 11 * 128,
               outH + (size_t)row0 * 33, outL + (size_t)row0 * 33, nullptr);
}

// Fused tail: levels d=5..0, one batch per block; 32 row-slots; inter-level via LDS.
__global__ __launch_bounds__(THREADS, 2)
void tail_kernel(const float* __restrict__ feat,
                 const unsigned short* __restrict__ g6H, const unsigned short* __restrict__ g6L,
                 const unsigned short* __restrict__ warena, const float* __restrict__ barena,
                 float* __restrict__ out)
{
  __shared__ unsigned short Ah[32 * KSTR];
  __shared__ unsigned short Al[32 * KSTR];
  __shared__ unsigned short oH[32 * 33];
  __shared__ unsigned short oL[32 * 33];
  const int tid = threadIdx.x;
  const int b = blockIdx.x;

  for (int d = 5; d >= 0; --d) {
    const int n = 1 << d;
    for (int e = tid; e < 32 * 64; e += THREADS) {
      const int m = e >> 6;
      const int c = e & 63;
      const int i = m & (n - 1);          // clamp; junk rows harmless
      if (c < 16) {
        const float2 v = *(const float2*)&feat[((size_t)b * NINT + (n - 1) + i) * FINT + 2 * c];
        *(unsigned int*)&Ah[m * KSTR + 2 * c] = pack_hi_trunc(v.x, v.y);
        *(unsigned int*)&Al[m * KSTR + 2 * c] = pack_lo_rne(v.x - trunc_bf(v.x), v.y - trunc_bf(v.y));
      } else if (c < 49) {
        const int p = c - 16;
        const unsigned short* sH = (d == 5) ? g6H : oH;
        const unsigned short* sL = (d == 5) ? g6L : oL;
        const size_t c0 = (d == 5) ? ((size_t)b * 64 + 2 * i) * 33 : (size_t)(2 * i) * 33;
        *(unsigned int*)&Ah[m * KSTR + 32 + 2 * p] = *(const unsigned int*)&sH[c0 + 2 * p];
        *(unsigned int*)&Al[m * KSTR + 32 + 2 * p] = *(const unsigned int*)&sL[c0 + 2 * p];
      } else {
        const int z = c - 49;
        *(unsigned int*)&Ah[m * KSTR + 98 + 2 * z] = 0u;
        *(unsigned int*)&Al[m * KSTR + 98 + 2 * z] = 0u;
      }
    }
    __syncthreads();

#pragma unroll
    for (int l = 6; l <= 10; ++l)
      dense_layer<4, 1>(Ah, Al, warena + l * 2 * MATSZ, warena + l * 2 * MATSZ + MATSZ, barena + l * 128);
    out_layer<1>(Ah, Al, warena + 11 * 2 * MATSZ, warena + 11 * 2 * MATSZ + MATSZ, barena + 11 * 128,
                 oH, oL, (d == 0) ? (out + b) : nullptr);
    __syncthreads();
  }
}

// Pre-split + pack all 12 weight matrices into fragment-major hi/lo arenas + biases.
__global__ void prep_kernel(const float* __restrict__ lW_in, const float* __restrict__ lW_hid,
                            const float* __restrict__ lW_out, const float* __restrict__ lb_in,
                            const float* __restrict__ lb_hid, const float* __restrict__ lb_out,
                            const float* __restrict__ iW_in, const float* __restrict__ iW_hid,
                            const float* __restrict__ iW_out, const float* __restrict__ ib_in,
                            const float* __restrict__ ib_hid, const float* __restrict__ ib_out,
                            unsigned short* __restrict__ warena, float* __restrict__ barena)
{
  const int id = blockIdx.y;
  const float* W; const float* bs; int K, N;
  if (id == 0)       { W = lW_in;                       bs = lb_in;                  K = FLEAF; N = Hh; }
  else if (id <= 4)  { W = lW_hid + (id - 1) * Hh * Hh; bs = lb_hid + (id - 1) * Hh; K = Hh;    N = Hh; }
  else if (id == 5)  { W = lW_out;                      bs = lb_out;                 K = Hh;    N = OUTC; }
  else if (id == 6)  { W = iW_in;                       bs = ib_in;                  K = FINT + 2 * OUTC; N = Hh; }
  else if (id <= 10) { W = iW_hid + (id - 7) * Hh * Hh; bs = ib_hid + (id - 7) * Hh; K = Hh;    N = Hh; }
  else               { W = iW_out;                      bs = ib_out;                 K = Hh;    N = OUTC; }

  unsigned short* dh = warena + id * 2 * MATSZ;
  unsigned short* dl = dh + MATSZ;
  const int e = blockIdx.x * THREADS + threadIdx.x;
  if (e < MATSZ) {
    const int ntg  = e >> 11;
    const int kc   = (e >> 9) & 3;
    const int lane = (e >> 3) & 63;
    const int j    = e & 7;
    const int quad = lane >> 4;
    const int l16  = lane & 15;
    const int nn = ntg * 16 + l16;
    const int kk = kc * 32 + quad * 8 + j;
    const float v = (kk < K && nn < N) ? W[(size_t)kk * N + nn] : 0.f;
    const unsigned short h = f2bf_rne(v);
    dh[e] = h;
    dl[e] = f2bf_rne(v - bf2f(h));
  }
  if (blockIdx.x == 0 && threadIdx.x < 128)
    barena[id * 128 + threadIdx.x] = (threadIdx.x < N) ? bs[threadIdx.x] : 0.f;
}

extern "C" void kernel_launch(void* const* d_in, const int* in_sizes, int n_in,
                              void* d_out, int out_size, void* d_ws, size_t ws_size,
                              hipStream_t stream) {
  const float* leaf_feat = (const float*)d_in[0];
  const float* int_feat  = (const float*)d_in[1];
  const float* lW_in  = (const float*)d_in[2];
  const float* lb_in  = (const float*)d_in[3];
  const float* lW_hid = (const float*)d_in[4];
  const float* lb_hid = (const float*)d_in[5];
  const float* lW_out = (const float*)d_in[6];
  const float* lb_out = (const float*)d_in[7];
  const float* iW_in  = (const float*)d_in[8];
  const float* ib_in  = (const float*)d_in[9];
  const float* iW_hid = (const float*)d_in[10];
  const float* ib_hid = (const float*)d_in[11];
  const float* iW_out = (const float*)d_in[12];
  const float* ib_out = (const float*)d_in[13];
  float* out = (float*)d_out;

  const size_t rowsA = (size_t)Bn * 1024;    // 524288
  const size_t rowsB = rowsA / 2;            // 262144
  unsigned short* AH = (unsigned short*)d_ws;
  unsigned short* AL = AH + rowsA * 33;
  unsigned short* BH = AL + rowsA * 33;
  unsigned short* BL = BH + rowsB * 33;
  unsigned short* warena = BL + rowsB * 33;
  float* barena = (float*)(warena + 24 * MATSZ);

  prep_kernel<<<dim3(MATSZ / THREADS, 12), THREADS, 0, stream>>>(
      lW_in, lW_hid, lW_out, lb_in, lb_hid, lb_out,
      iW_in, iW_hid, iW_out, ib_in, ib_hid, ib_out, warena, barena);

  leaf_kernel<<<(Bn * 1024) / 128, THREADS, 0, stream>>>(leaf_feat, warena, barena, AH, AL);

  int_kernel<<<2048, THREADS, 0, stream>>>(int_feat, AH, AL, warena, barena, BH, BL, 512, 9);
  int_kernel<<<1024, THREADS, 0, stream>>>(int_feat, BH, BL, warena, barena, AH, AL, 256, 8);
  int_kernel<<< 512, THREADS, 0, stream>>>(int_feat, AH, AL, warena, barena, BH, BL, 128, 7);
  int_kernel<<< 256, THREADS, 0, stream>>>(int_feat, BH, BL, warena, barena, AH, AL,  64, 6);

  tail_kernel<<<Bn, THREADS, 0, stream>>>(int_feat, AH, AL, warena, barena, out);
}

// Round 5
// 1183.558 us; speedup vs baseline: 1.2692x; 1.2692x over previous
//
#include <hip/hip_runtime.h>
#include <cstdint>
#include <cstddef>

// ---- problem constants ----
constexpr int Bn    = 512;
constexpr int NINT  = 1023;
constexpr int FLEAF = 64;
constexpr int FINT  = 32;
constexpr int Hh    = 128;
constexpr int OUTC  = 33;

#define THREADS 256
constexpr int KSTR  = 136;      // Act LDS k-stride (u16): 272B rows -> conflict-free b128
constexpr int MATSZ = 16384;    // u16 per half-matrix: 8 ntg x 4 kc x 64 lanes x 8

using short8 = __attribute__((ext_vector_type(8))) short;
using f32x4  = __attribute__((ext_vector_type(4))) float;

__device__ __forceinline__ unsigned int f2bf_rne_u(float f) {
  unsigned int u = __float_as_uint(f);
  u += 0x7fffu + ((u >> 16) & 1);
  return u;
}
__device__ __forceinline__ unsigned short f2bf_rne(float f) {
  return (unsigned short)(f2bf_rne_u(f) >> 16);
}
__device__ __forceinline__ float bf2f(unsigned short h) {
  return __uint_as_float((unsigned int)h << 16);
}
__device__ __forceinline__ float trunc_bf(float a) {
  return __uint_as_float(__float_as_uint(a) & 0xffff0000u);
}
__device__ __forceinline__ unsigned int pack_hi_trunc(float a, float b) {
  return (__float_as_uint(a) >> 16) | (__float_as_uint(b) & 0xffff0000u);
}
__device__ __forceinline__ unsigned int pack_lo_rne(float a, float b) {
  return (f2bf_rne_u(a) >> 16) | (f2bf_rne_u(b) & 0xffff0000u);
}

// Packed fragment-major weight frag address: ((ntg*4 + kc)*64 + lane)*8 u16 = 16B/lane.
__device__ __forceinline__ const short8* wfrag(const unsigned short* W, int ntg, int kc, int lane) {
  return (const short8*)&W[(((ntg << 2) + kc) << 6 | lane) << 3];
}

// Dense layer, wave grid 2x2 over a 128-row tile (wm: 64-row half, wn: 64-col half).
// D = W x Act^T (A-op = W[n][k], B-op = Act[m][k]); C: col=m=l16, row=n=quad*4+r.
// In-place ReLU(Act @ W + b) into Ah/Al. Weights streamed from global (L2-resident).
template <int KC>
__device__ __forceinline__ void dense_layer(
    unsigned short* Ah, unsigned short* Al,
    const unsigned short* __restrict__ Wh, const unsigned short* __restrict__ Wl,
    const float* __restrict__ bias)
{
  const int tid  = threadIdx.x;
  const int wave = tid >> 6;
  const int wn   = wave & 1;
  const int wm   = wave >> 1;
  const int lane = tid & 63;
  const int quad = lane >> 4;
  const int l16  = lane & 15;
  const int mbase = wm * 64;

  float4 bv[4];
#pragma unroll
  for (int nt = 0; nt < 4; ++nt)
    bv[nt] = *(const float4*)&bias[wn * 64 + nt * 16 + quad * 4];

  f32x4 c[4][4];
#pragma unroll
  for (int mt = 0; mt < 4; ++mt)
#pragma unroll
    for (int nt = 0; nt < 4; ++nt) c[mt][nt] = (f32x4){0.f, 0.f, 0.f, 0.f};

#pragma unroll 2
  for (int kc = 0; kc < KC; ++kc) {
    const int k0 = kc * 32 + quad * 8;
    short8 wh[4], wl[4];
#pragma unroll
    for (int nt = 0; nt < 4; ++nt) {
      wh[nt] = *wfrag(Wh, wn * 4 + nt, kc, lane);
      wl[nt] = *wfrag(Wl, wn * 4 + nt, kc, lane);
    }
    short8 ah[4], al[4];
#pragma unroll
    for (int mt = 0; mt < 4; ++mt) {
      ah[mt] = *(const short8*)&Ah[(mbase + mt * 16 + l16) * KSTR + k0];
      al[mt] = *(const short8*)&Al[(mbase + mt * 16 + l16) * KSTR + k0];
    }
#pragma unroll
    for (int mt = 0; mt < 4; ++mt)
#pragma unroll
      for (int nt = 0; nt < 4; ++nt)
        c[mt][nt] = __builtin_amdgcn_mfma_f32_16x16x32_bf16(wh[nt], ah[mt], c[mt][nt], 0, 0, 0);
#pragma unroll
    for (int mt = 0; mt < 4; ++mt)
#pragma unroll
      for (int nt = 0; nt < 4; ++nt)
        c[mt][nt] = __builtin_amdgcn_mfma_f32_16x16x32_bf16(wh[nt], al[mt], c[mt][nt], 0, 0, 0);
#pragma unroll
    for (int mt = 0; mt < 4; ++mt)
#pragma unroll
      for (int nt = 0; nt < 4; ++nt)
        c[mt][nt] = __builtin_amdgcn_mfma_f32_16x16x32_bf16(wl[nt], ah[mt], c[mt][nt], 0, 0, 0);
  }
  __syncthreads();  // all Act reads complete before in-place overwrite

#pragma unroll
  for (int mt = 0; mt < 4; ++mt) {
    const int m = mbase + mt * 16 + l16;
#pragma unroll
    for (int nt = 0; nt < 4; ++nt) {
      const int nb = wn * 64 + nt * 16 + quad * 4;
      float v0 = fmaxf(c[mt][nt][0] + bv[nt].x, 0.f);
      float v1 = fmaxf(c[mt][nt][1] + bv[nt].y, 0.f);
      float v2 = fmaxf(c[mt][nt][2] + bv[nt].z, 0.f);
      float v3 = fmaxf(c[mt][nt][3] + bv[nt].w, 0.f);
      const unsigned int h0 = pack_hi_trunc(v0, v1);
      const unsigned int h1 = pack_hi_trunc(v2, v3);
      const unsigned int l0 = pack_lo_rne(v0 - trunc_bf(v0), v1 - trunc_bf(v1));
      const unsigned int l1 = pack_lo_rne(v2 - trunc_bf(v2), v3 - trunc_bf(v3));
      *(uint2*)&Ah[m * KSTR + nb] = make_uint2(h0, h1);
      *(uint2*)&Al[m * KSTR + nb] = make_uint2(l0, l1);
    }
  }
  __syncthreads();
}

// Output layer: [128 x 128] @ [128 x 33] + bias (linear), u16 hi/lo rows stride 33.
// wn=0 -> ntg {0,1}; wn=1 -> ntg {2}. If nfinal>0: rows m<nfinal, n==0 -> finalOut[m].
__device__ __forceinline__ void out_layer(
    const unsigned short* Ah, const unsigned short* Al,
    const unsigned short* __restrict__ Wh, const unsigned short* __restrict__ Wl,
    const float* __restrict__ bias,
    unsigned short* outH, unsigned short* outL, float* finalOut, int nfinal)
{
  const int tid  = threadIdx.x;
  const int wave = tid >> 6;
  const int wn   = wave & 1;
  const int wm   = wave >> 1;
  const int lane = tid & 63;
  const int quad = lane >> 4;
  const int l16  = lane & 15;
  const int mbase = wm * 64;

#pragma unroll
  for (int nt = 0; nt < 2; ++nt) {
    const int ntg = wn * 2 + nt;
    if (ntg >= 3) continue;
    f32x4 c[4];
#pragma unroll
    for (int mt = 0; mt < 4; ++mt) c[mt] = (f32x4){0.f, 0.f, 0.f, 0.f};
#pragma unroll
    for (int kc = 0; kc < 4; ++kc) {
      const int k0 = kc * 32 + quad * 8;
      const short8 bwh = *wfrag(Wh, ntg, kc, lane);
      const short8 bwl = *wfrag(Wl, ntg, kc, lane);
#pragma unroll
      for (int mt = 0; mt < 4; ++mt) {
        const short8 ah = *(const short8*)&Ah[(mbase + mt * 16 + l16) * KSTR + k0];
        const short8 al = *(const short8*)&Al[(mbase + mt * 16 + l16) * KSTR + k0];
        c[mt] = __builtin_amdgcn_mfma_f32_16x16x32_bf16(bwh, ah, c[mt], 0, 0, 0);
        c[mt] = __builtin_amdgcn_mfma_f32_16x16x32_bf16(bwh, al, c[mt], 0, 0, 0);
        c[mt] = __builtin_amdgcn_mfma_f32_16x16x32_bf16(bwl, ah, c[mt], 0, 0, 0);
      }
    }
    const int nb = ntg * 16 + quad * 4;
    const float4 bvv = *(const float4*)&bias[nb];
    const float bvr[4] = {bvv.x, bvv.y, bvv.z, bvv.w};
#pragma unroll
    for (int mt = 0; mt < 4; ++mt) {
      const int m = mbase + mt * 16 + l16;
#pragma unroll
      for (int r = 0; r < 4; ++r) {
        const int n = nb + r;
        const float v = c[mt][r] + bvr[r];
        if (n < OUTC) {
          outH[m * 33 + n] = (unsigned short)(__float_as_uint(v) >> 16);
          outL[m * 33 + n] = f2bf_rne(v - trunc_bf(v));
        }
        if (nfinal > 0 && n == 0 && m < nfinal) finalOut[m] = v;
      }
    }
  }
}

__global__ __launch_bounds__(THREADS, 2)
void leaf_kernel(const float* __restrict__ X,
                 const unsigned short* __restrict__ warena,
                 const float* __restrict__ barena,
                 unsigned short* __restrict__ outH, unsigned short* __restrict__ outL)
{
  __shared__ unsigned short Ah[128 * KSTR];
  __shared__ unsigned short Al[128 * KSTR];
  const int row_base = blockIdx.x * 128;
  const int tid = threadIdx.x;

  for (int e = tid; e < 128 * 16; e += THREADS) {
    const int r  = e >> 4;
    const int k0 = (e & 15) << 2;
    const float4 v = *(const float4*)&X[(size_t)(row_base + r) * FLEAF + k0];
    const unsigned int h0 = pack_hi_trunc(v.x, v.y);
    const unsigned int h1 = pack_hi_trunc(v.z, v.w);
    const unsigned int l0 = pack_lo_rne(v.x - trunc_bf(v.x), v.y - trunc_bf(v.y));
    const unsigned int l1 = pack_lo_rne(v.z - trunc_bf(v.z), v.w - trunc_bf(v.w));
    *(uint2*)&Ah[r * KSTR + k0] = make_uint2(h0, h1);
    *(uint2*)&Al[r * KSTR + k0] = make_uint2(l0, l1);
  }
  __syncthreads();

  dense_layer<2>(Ah, Al, warena + 0 * 2 * MATSZ, warena + 0 * 2 * MATSZ + MATSZ, barena + 0 * 128);
#pragma unroll
  for (int l = 1; l <= 4; ++l)
    dense_layer<4>(Ah, Al, warena + l * 2 * MATSZ, warena + l * 2 * MATSZ + MATSZ, barena + l * 128);
  out_layer(Ah, Al, warena + 5 * 2 * MATSZ, warena + 5 * 2 * MATSZ + MATSZ, barena + 5 * 128,
            outH + (size_t)row_base * 33, outL + (size_t)row_base * 33, nullptr, 0);
}

__global__ __launch_bounds__(THREADS, 2)
void int_kernel(const float* __restrict__ feat,
                const unsigned short* __restrict__ prevH, const unsigned short* __restrict__ prevL,
                const unsigned short* __restrict__ warena, const float* __restrict__ barena,
                unsigned short* __restrict__ outH, unsigned short* __restrict__ outL,
                int n, int logn)
{
  __shared__ unsigned short Ah[128 * KSTR];
  __shared__ unsigned short Al[128 * KSTR];
  const int tid = threadIdx.x;
  const int row0 = blockIdx.x * 128;

  // staging: chunks per row: 16 feat-u32, 33 child-u32, 15 zero-u32 (coalesced in-row)
  for (int e = tid; e < 128 * 64; e += THREADS) {
    const int m = e >> 6;
    const int c = e & 63;
    const int row = row0 + m;
    const int b = row >> logn;
    const int i = row & (n - 1);
    if (c < 16) {
      const float2 v = *(const float2*)&feat[((size_t)b * NINT + (n - 1) + i) * FINT + 2 * c];
      *(unsigned int*)&Ah[m * KSTR + 2 * c] = pack_hi_trunc(v.x, v.y);
      *(unsigned int*)&Al[m * KSTR + 2 * c] = pack_lo_rne(v.x - trunc_bf(v.x), v.y - trunc_bf(v.y));
    } else if (c < 49) {
      const int p = c - 16;
      const size_t c0 = ((size_t)b * (n << 1) + (i << 1)) * 33;
      *(unsigned int*)&Ah[m * KSTR + 32 + 2 * p] = *(const unsigned int*)&prevH[c0 + 2 * p];
      *(unsigned int*)&Al[m * KSTR + 32 + 2 * p] = *(const unsigned int*)&prevL[c0 + 2 * p];
    } else {
      const int z = c - 49;
      *(unsigned int*)&Ah[m * KSTR + 98 + 2 * z] = 0u;
      *(unsigned int*)&Al[m * KSTR + 98 + 2 * z] = 0u;
    }
  }
  __syncthreads();

#pragma unroll
  for (int l = 6; l <= 10; ++l)
    dense_layer<4>(Ah, Al, warena + l * 2 * MATSZ, warena + l * 2 * MATSZ + MATSZ, barena + l * 128);
  out_layer(Ah, Al, warena + 11 * 2 * MATSZ, warena + 11 * 2 * MATSZ + MATSZ, barena + 11 * 128,
            outH + (size_t)row0 * 33, outL + (size_t)row0 * 33, nullptr, 0);
}

// Fused tail: levels d=4..0; 8 batches per block (64 blocks). 128 row-slots per level:
// slot = g*n + i (g = batch-in-group, i = node). Children of (g,i) at level d are
// slots (g*2n + 2i, +1) of level d+1 (LDS), except d=4 which reads d=5 output (global).
__global__ __launch_bounds__(THREADS, 1)
void tail_kernel(const float* __restrict__ feat,
                 const unsigned short* __restrict__ g5H, const unsigned short* __restrict__ g5L,
                 const unsigned short* __restrict__ warena, const float* __restrict__ barena,
                 float* __restrict__ out)
{
  __shared__ unsigned short Ah[128 * KSTR];
  __shared__ unsigned short Al[128 * KSTR];
  __shared__ unsigned short oH[128 * 33];
  __shared__ unsigned short oL[128 * 33];
  const int tid = threadIdx.x;
  const int bb = blockIdx.x * 8;    // first batch of this block's group

  for (int d = 4; d >= 0; --d) {
    const int n = 1 << d;
    for (int e = tid; e < 128 * 64; e += THREADS) {
      const int m = e >> 6;
      const int c = e & 63;
      const int g = (m >> d) & 7;       // wraps for junk slots -> duplicate real rows
      const int i = m & (n - 1);
      const int b = bb + g;
      if (c < 16) {
        const float2 v = *(const float2*)&feat[((size_t)b * NINT + (n - 1) + i) * FINT + 2 * c];
        *(unsigned int*)&Ah[m * KSTR + 2 * c] = pack_hi_trunc(v.x, v.y);
        *(unsigned int*)&Al[m * KSTR + 2 * c] = pack_lo_rne(v.x - trunc_bf(v.x), v.y - trunc_bf(v.y));
      } else if (c < 49) {
        const int p = c - 16;
        if (d == 4) {
          const size_t c0 = ((size_t)b * 32 + 2 * i) * 33;
          *(unsigned int*)&Ah[m * KSTR + 32 + 2 * p] = *(const unsigned int*)&g5H[c0 + 2 * p];
          *(unsigned int*)&Al[m * KSTR + 32 + 2 * p] = *(const unsigned int*)&g5L[c0 + 2 * p];
        } else {
          const size_t c0 = (size_t)((g << (d + 1)) + 2 * i) * 33;
          *(unsigned int*)&Ah[m * KSTR + 32 + 2 * p] = *(const unsigned int*)&oH[c0 + 2 * p];
          *(unsigned int*)&Al[m * KSTR + 32 + 2 * p] = *(const unsigned int*)&oL[c0 + 2 * p];
        }
      } else {
        const int z = c - 49;
        *(unsigned int*)&Ah[m * KSTR + 98 + 2 * z] = 0u;
        *(unsigned int*)&Al[m * KSTR + 98 + 2 * z] = 0u;
      }
    }
    __syncthreads();

#pragma unroll
    for (int l = 6; l <= 10; ++l)
      dense_layer<4>(Ah, Al, warena + l * 2 * MATSZ, warena + l * 2 * MATSZ + MATSZ, barena + l * 128);
    out_layer(Ah, Al, warena + 11 * 2 * MATSZ, warena + 11 * 2 * MATSZ + MATSZ, barena + 11 * 128,
              oH, oL, out + bb, (d == 0) ? 8 : 0);
    __syncthreads();   // oH/oL writes visible before next level's staging reads
  }
}

// Pre-split + pack all 12 weight matrices into fragment-major hi/lo arenas + biases.
__global__ void prep_kernel(const float* __restrict__ lW_in, const float* __restrict__ lW_hid,
                            const float* __restrict__ lW_out, const float* __restrict__ lb_in,
                            const float* __restrict__ lb_hid, const float* __restrict__ lb_out,
                            const float* __restrict__ iW_in, const float* __restrict__ iW_hid,
                            const float* __restrict__ iW_out, const float* __restrict__ ib_in,
                            const float* __restrict__ ib_hid, const float* __restrict__ ib_out,
                            unsigned short* __restrict__ warena, float* __restrict__ barena)
{
  const int id = blockIdx.y;
  const float* W; const float* bs; int K, N;
  if (id == 0)       { W = lW_in;                       bs = lb_in;                  K = FLEAF; N = Hh; }
  else if (id <= 4)  { W = lW_hid + (id - 1) * Hh * Hh; bs = lb_hid + (id - 1) * Hh; K = Hh;    N = Hh; }
  else if (id == 5)  { W = lW_out;                      bs = lb_out;                 K = Hh;    N = OUTC; }
  else if (id == 6)  { W = iW_in;                       bs = ib_in;                  K = FINT + 2 * OUTC; N = Hh; }
  else if (id <= 10) { W = iW_hid + (id - 7) * Hh * Hh; bs = ib_hid + (id - 7) * Hh; K = Hh;    N = Hh; }
  else               { W = iW_out;                      bs = ib_out;                 K = Hh;    N = OUTC; }

  unsigned short* dh = warena + id * 2 * MATSZ;
  unsigned short* dl = dh + MATSZ;
  const int e = blockIdx.x * THREADS + threadIdx.x;
  if (e < MATSZ) {
    const int ntg  = e >> 11;
    const int kc   = (e >> 9) & 3;
    const int lane = (e >> 3) & 63;
    const int j    = e & 7;
    const int quad = lane >> 4;
    const int l16  = lane & 15;
    const int nn = ntg * 16 + l16;
    const int kk = kc * 32 + quad * 8 + j;
    const float v = (kk < K && nn < N) ? W[(size_t)kk * N + nn] : 0.f;
    const unsigned short h = f2bf_rne(v);
    dh[e] = h;
    dl[e] = f2bf_rne(v - bf2f(h));
  }
  if (blockIdx.x == 0 && threadIdx.x < 128)
    barena[id * 128 + threadIdx.x] = (threadIdx.x < N) ? bs[threadIdx.x] : 0.f;
}

extern "C" void kernel_launch(void* const* d_in, const int* in_sizes, int n_in,
                              void* d_out, int out_size, void* d_ws, size_t ws_size,
                              hipStream_t stream) {
  const float* leaf_feat = (const float*)d_in[0];
  const float* int_feat  = (const float*)d_in[1];
  const float* lW_in  = (const float*)d_in[2];
  const float* lb_in  = (const float*)d_in[3];
  const float* lW_hid = (const float*)d_in[4];
  const float* lb_hid = (const float*)d_in[5];
  const float* lW_out = (const float*)d_in[6];
  const float* lb_out = (const float*)d_in[7];
  const float* iW_in  = (const float*)d_in[8];
  const float* ib_in  = (const float*)d_in[9];
  const float* iW_hid = (const float*)d_in[10];
  const float* ib_hid = (const float*)d_in[11];
  const float* iW_out = (const float*)d_in[12];
  const float* ib_out = (const float*)d_in[13];
  float* out = (float*)d_out;

  const size_t rowsA = (size_t)Bn * 1024;    // 524288
  const size_t rowsB = rowsA / 2;            // 262144
  unsigned short* AH = (unsigned short*)d_ws;
  unsigned short* AL = AH + rowsA * 33;
  unsigned short* BH = AL + rowsA * 33;
  unsigned short* BL = BH + rowsB * 33;
  unsigned short* warena = BL + rowsB * 33;
  float* barena = (float*)(warena + 24 * MATSZ);

  prep_kernel<<<dim3(MATSZ / THREADS, 12), THREADS, 0, stream>>>(
      lW_in, lW_hid, lW_out, lb_in, lb_hid, lb_out,
      iW_in, iW_hid, iW_out, ib_in, ib_hid, ib_out, warena, barena);

  leaf_kernel<<<(Bn * 1024) / 128, THREADS, 0, stream>>>(leaf_feat, warena, barena, AH, AL);

  int_kernel<<<2048, THREADS, 0, stream>>>(int_feat, AH, AL, warena, barena, BH, BL, 512, 9);
  int_kernel<<<1024, THREADS, 0, stream>>>(int_feat, BH, BL, warena, barena, AH, AL, 256, 8);
  int_kernel<<< 512, THREADS, 0, stream>>>(int_feat, AH, AL, warena, barena, BH, BL, 128, 7);
  int_kernel<<< 256, THREADS, 0, stream>>>(int_feat, BH, BL, warena, barena, AH, AL,  64, 6);
  int_kernel<<< 128, THREADS, 0, stream>>>(int_feat, AH, AL, warena, barena, BH, BL,  32, 5);

  tail_kernel<<<64, THREADS, 0, stream>>>(int_feat, BH, BL, warena, barena, out);
}